// Round 3
// baseline (141.566 us; speedup 1.0000x reference)
//
#include <hip/hip_runtime.h>
#include <math.h>

#define DK 32
#define OUT_DIM 32

typedef float    f32x4 __attribute__((ext_vector_type(4)));
typedef _Float16 h2    __attribute__((ext_vector_type(2)));
typedef _Float16 h8    __attribute__((ext_vector_type(8)));

#if __has_builtin(__builtin_amdgcn_fdot2)
#define FDOT2(a, b, c) __builtin_amdgcn_fdot2((a), (b), (c), false)
#else
#define FDOT2(a, b, c) ((c) + (float)(a).x * (float)(b).x + (float)(a).y * (float)(b).y)
#endif

#if __has_builtin(__builtin_amdgcn_exp2f)
#define EXP2F(x) __builtin_amdgcn_exp2f(x)
#else
#define EXP2F(x) exp2f(x)
#endif

__device__ __forceinline__ h2 as_h2(unsigned u) {
    union { unsigned u; h2 h; } v; v.u = u; return v.h;
}
__device__ __forceinline__ unsigned as_u32(h2 h) {
    union { unsigned u; h2 h; } v; v.h = h; return v.u;
}
__device__ __forceinline__ h2 shfl_xor_h2(h2 v, int m) {
    union { unsigned u; h2 h; } x; x.h = v;
    x.u = (unsigned)__shfl_xor((int)x.u, m);
    return x.h;
}

// prep (R13-proven): int4-vectorized dst boundary scan (4 edges/thread) +
// uint4 KV pack (one thread per node-chunk). KVH chunk c of node s =
// {K01,K23,V01,V23} f16 pairs for dims 4c..4c+3.
__global__ void prep_kernel(const int* __restrict__ dst,
                            const float4* __restrict__ K4,
                            const float4* __restrict__ V4,
                            int E, int N,
                            int* __restrict__ row_ptr,
                            uint4* __restrict__ KVH) {
    const int t  = blockIdx.x * blockDim.x + threadIdx.x;
    const int e0 = t * 4;
    if (e0 < E) {
        int cur[4];
        if (e0 + 4 <= E) {
            const int4 dd = *(const int4*)(dst + e0);
            cur[0] = dd.x; cur[1] = dd.y; cur[2] = dd.z; cur[3] = dd.w;
        } else {
#pragma unroll
            for (int k = 0; k < 4; ++k)
                cur[k] = (e0 + k < E) ? dst[e0 + k] : 0;
        }
        int prev = (e0 == 0) ? -1 : dst[e0 - 1];
#pragma unroll
        for (int k = 0; k < 4; ++k) {
            const int ee = e0 + k;
            if (ee < E) {
                for (int j = prev + 1; j <= cur[k]; ++j) row_ptr[j] = ee;
                if (ee == E - 1)
                    for (int j = cur[k] + 1; j <= N; ++j) row_ptr[j] = E;
                prev = cur[k];
            }
        }
    }
    if (t < N * 8) {
        const float4 kf = K4[t];
        const float4 vf = V4[t];
        h2 k01, k23, v01, v23;
        k01.x = (_Float16)kf.x;  k01.y = (_Float16)kf.y;
        k23.x = (_Float16)kf.z;  k23.y = (_Float16)kf.w;
        v01.x = (_Float16)vf.x;  v01.y = (_Float16)vf.y;
        v23.x = (_Float16)vf.z;  v23.y = (_Float16)vf.w;
        uint4 o;
        o.x = as_u32(k01); o.y = as_u32(k23); o.z = as_u32(v01); o.w = as_u32(v23);
        KVH[t] = o;
    }
}

// Fallback-path row_ptr builder (ws too small for KV).
__global__ void build_row_ptr_kernel(const int* __restrict__ dst, int E, int N,
                                     int* __restrict__ row_ptr) {
    int e = blockIdx.x * blockDim.x + threadIdx.x;
    if (e >= E) return;
    int cur  = dst[e];
    int prev = (e == 0) ? -1 : dst[e - 1];
    for (int j = prev + 1; j <= cur; ++j) row_ptr[j] = e;
    if (e == E - 1) {
        for (int j = cur + 1; j <= N; ++j) row_ptr[j] = E;
    }
}

// R14: ONE NODE PER WAVE, straight-line gather prologue.
// Post-mortem R12/R13: pipelining returned ~0 because the structure is the
// problem: 4 sequential node-batches per step (4 dots + 12 shfl + 4 exp),
// 41% clamped-slot waste, prologue amortized over ~2 iterations. With one
// node/wave, T = ceil(deg/8) <= 4 for ~99.99% of Poisson(16) nodes, so the
// whole gather phase is straight-line: up to 4 independent src loads, then
// up to 4 independent KV gathers -> exactly ONE serial src->KV round-trip
// per wave. Per-step VALU drops 4x, VGPR ~40 -> high occupancy, 8x more
// waves to hide the single round-trip. Rare deg>32 tail handled serially.
// Block = 512 thr = 8 waves = 8 nodes; verified MFMA epilogue kept (A-tile
// rows 0-7 valid, 8-15 zeroed; stores guarded to rows < 8).
__global__ __launch_bounds__(512) void gat_fused_kernel(
    const float* __restrict__ X, const uint4* __restrict__ KV,
    const float* __restrict__ Wo, const float* __restrict__ bo,
    const int* __restrict__ src, const int* __restrict__ row_ptr,
    float* __restrict__ out, int N) {

    __shared__ uint4 s_part[16 * 17];   // 16-row A-tile, row stride 17 (pad)

    const int tid  = threadIdx.x;
    const int w    = tid >> 6;    // wave 0..7 = node offset in block
    const int lane = tid & 63;
    const int g    = lane >> 3;   // edge slot 0..7
    const int c    = lane & 7;    // dim chunk 0..7

    const int n_blk = blockIdx.x * 8;
    const int n     = n_blk + w;

    // zero A-tile rows 8..15 (read by MFMA, never stored)
    if (tid < 136) {
        uint4 z; z.x = 0; z.y = 0; z.z = 0; z.w = 0;
        s_part[136 + tid] = z;
    }

    // wave-uniform segment bounds (readfirstlane -> SALU)
    const int B    = __builtin_amdgcn_readfirstlane(row_ptr[min(n, N)]);
    const int En   = __builtin_amdgcn_readfirstlane(row_ptr[min(n + 1, N)]);
    const int deg  = En - B;
    const int dcap = max(En - 1, 0);
    const int T    = (deg + 7) >> 3;

    const float scale = 0.03125f * 1.44269504f;  // 1/dk * log2(e) for exp2
    const float4 qf = ((const float4*)X)[min(n, N - 1) * 8 + c];
    h2 q01, q23;
    q01.x = (_Float16)(qf.x * scale);  q01.y = (_Float16)(qf.y * scale);
    q23.x = (_Float16)(qf.z * scale);  q23.y = (_Float16)(qf.w * scale);

    float l = 0.0f;
    h2 a01 = (h2)0, a23 = (h2)0;

    auto step = [&](const uint4& Bf, int t) {
        float p = FDOT2(as_h2(Bf.y), q23, FDOT2(as_h2(Bf.x), q01, 0.0f));
        p += __shfl_xor(p, 1);
        p += __shfl_xor(p, 2);
        p += __shfl_xor(p, 4);
        const float wt = (t * 8 + g < deg) ? EXP2F(p) : 0.0f;
        l += wt;
        h2 wh; wh.x = (_Float16)wt; wh.y = wh.x;
        a01 += wh * as_h2(Bf.z);
        a23 += wh * as_h2(Bf.w);
    };

    if (T > 0) {
        const int base = B + g;
        // all src loads issued up front (independent, ~1 line each)
        const int s0 = src[min(base, dcap)];
        int s1 = 0, s2 = 0, s3 = 0;
        if (T > 1) s1 = src[min(base + 8,  dcap)];
        if (T > 2) s2 = src[min(base + 16, dcap)];
        if (T > 3) s3 = src[min(base + 24, dcap)];
        // all KV gathers issued together (4 independent chains)
        uint4 P0, P1, P2, P3;
        P0 = KV[s0 * 8 + c];
        if (T > 1) P1 = KV[s1 * 8 + c];
        if (T > 2) P2 = KV[s2 * 8 + c];
        if (T > 3) P3 = KV[s3 * 8 + c];

        step(P0, 0);
        if (T > 1) step(P1, 1);
        if (T > 2) step(P2, 2);
        if (T > 3) step(P3, 3);

        // rare tail (deg > 32): serial, correctness path
        for (int t = 4; t < T; ++t) {
            const int sx = src[min(B + t * 8 + g, dcap)];
            const uint4 Px = KV[sx * 8 + c];
            step(Px, t);
        }
    }

    // per-node reduction: l over all slots; a folded to 4 slot-pair partials
    l   += __shfl_xor(l, 8);
    a01 += shfl_xor_h2(a01, 8);
    a23 += shfl_xor_h2(a23, 8);
    l += __shfl_xor(l, 16);
    l += __shfl_xor(l, 32);

    const float inv = (deg > 0) ? (1.0f / l) : 0.0f;
    h2 iv; iv.x = (_Float16)inv; iv.y = iv.x;
    a01 *= iv;  a23 *= iv;

    if ((g & 1) == 0) {                  // even slots hold pair sums
        unsigned* part32 = (unsigned*)s_part;
        const int off = w * 68 + (g >> 1) * 16 + c * 2;   // uint32 units
        part32[off]     = as_u32(a01);
        part32[off + 1] = as_u32(a23);
    }

    __syncthreads();

    // wave 0: projection for the block's 8 nodes via 16x16x32 f16 MFMA
    // (A rows 8..15 are zero; C rows 8..15 discarded)
    if (w == 0) {
        const int quad = lane >> 4;   // 0..3
        const int col  = lane & 15;

        union BF { h8 v; _Float16 u[8]; };
        BF bf0, bf1;
#pragma unroll
        for (int j2 = 0; j2 < 8; ++j2) {
            bf0.u[j2] = (_Float16)Wo[(quad * 8 + j2) * OUT_DIM + col];
            bf1.u[j2] = (_Float16)Wo[(quad * 8 + j2) * OUT_DIM + 16 + col];
        }
        const float bias0 = bo[col];
        const float bias1 = bo[16 + col];

        union AF { uint4 u; h8 v; };
        f32x4 C0 = {bias0, bias0, bias0, bias0};
        f32x4 C1 = {bias1, bias1, bias1, bias1};
#pragma unroll
        for (int cc = 0; cc < 4; ++cc) {
            AF a;
            a.u = s_part[col * 17 + cc * 4 + quad];      // ds_read_b128
            C0 = __builtin_amdgcn_mfma_f32_16x16x32_f16(a.v, bf0.v, C0, 0, 0, 0);
            C1 = __builtin_amdgcn_mfma_f32_16x16x32_f16(a.v, bf1.v, C1, 0, 0, 0);
        }
        // C/D layout: col = lane&15, row = quad*4 + reg (verified mapping)
        if (quad < 2) {                 // only rows 0..7 are real nodes
#pragma unroll
            for (int r = 0; r < 4; ++r) {
                const int n2 = n_blk + quad * 4 + r;
                if (n2 < N) {
                    out[n2 * OUT_DIM + col]      = C0[r];
                    out[n2 * OUT_DIM + 16 + col] = C1[r];
                }
            }
        }
    }
}

// ---- fallback (R4-proven fp32 path, used only if ws too small for KV) ----
__global__ __launch_bounds__(256) void gat_node_f32_kernel(
    const float* __restrict__ X, const float* __restrict__ Km,
    const float* __restrict__ Vm, const float* __restrict__ Wo,
    const float* __restrict__ bo, const int* __restrict__ src,
    const int* __restrict__ row_ptr, float* __restrict__ out, int N) {
    const int tid  = threadIdx.x;
    const int wave = tid >> 6;
    const int lane = tid & 63;
    const int g    = lane >> 3;
    const int c    = lane & 7;
    const int j    = lane & 31;
    const int half = lane >> 5;
    const int n = blockIdx.x * 4 + wave;
    if (n >= N) return;
    const int begin = row_ptr[n];
    const int end   = row_ptr[n + 1];
    const float4* X4 = (const float4*)X;
    const float4* K4 = (const float4*)Km;
    const float4* V4 = (const float4*)Vm;
    const float4 q4 = X4[n * 8 + c];
    float  l   = 0.0f;
    float4 acc = make_float4(0.0f, 0.0f, 0.0f, 0.0f);
    for (int e0 = begin; e0 < end; e0 += 16) {
        const int  ea = e0 + g;
        const int  eb = ea + 8;
        const bool va = ea < end;
        const bool vb = eb < end;
        const int sa = src[min(ea, end - 1)];
        const int sb = src[min(eb, end - 1)];
        const float4 ka  = K4[sa * 8 + c];
        const float4 kb  = K4[sb * 8 + c];
        const float4 vva = V4[sa * 8 + c];
        const float4 vvb = V4[sb * 8 + c];
        float pa = fmaf(ka.x, q4.x, fmaf(ka.y, q4.y, fmaf(ka.z, q4.z, ka.w * q4.w)));
        float pb = fmaf(kb.x, q4.x, fmaf(kb.y, q4.y, fmaf(kb.z, q4.z, kb.w * q4.w)));
        pa += __shfl_xor(pa, 1);  pb += __shfl_xor(pb, 1);
        pa += __shfl_xor(pa, 2);  pb += __shfl_xor(pb, 2);
        pa += __shfl_xor(pa, 4);  pb += __shfl_xor(pb, 4);
        const float wa = va ? __expf(pa * 0.03125f) : 0.0f;
        const float wb = vb ? __expf(pb * 0.03125f) : 0.0f;
        l += wa + wb;
        acc.x = fmaf(wa, vva.x, acc.x);  acc.y = fmaf(wa, vva.y, acc.y);
        acc.z = fmaf(wa, vva.z, acc.z);  acc.w = fmaf(wa, vva.w, acc.w);
        acc.x = fmaf(wb, vvb.x, acc.x);  acc.y = fmaf(wb, vvb.y, acc.y);
        acc.z = fmaf(wb, vvb.z, acc.z);  acc.w = fmaf(wb, vvb.w, acc.w);
    }
#pragma unroll
    for (int m = 8; m <= 32; m <<= 1) {
        l     += __shfl_xor(l, m);
        acc.x += __shfl_xor(acc.x, m);
        acc.y += __shfl_xor(acc.y, m);
        acc.z += __shfl_xor(acc.z, m);
        acc.w += __shfl_xor(acc.w, m);
    }
    const float inv = (end > begin) ? (1.0f / l) : 0.0f;
    float ag[4] = {acc.x, acc.y, acc.z, acc.w};
    float s = 0.0f;
#pragma unroll
    for (int k = 0; k < 32; ++k) {
        const float a = __int_as_float(
            __builtin_amdgcn_readlane(__float_as_int(ag[k & 3]), k >> 2));
        s = fmaf(a, Wo[k * OUT_DIM + j], s);
    }
    if (half == 0) {
        out[n * OUT_DIM + j] = fmaf(s, inv, bo[j]);
    }
}

extern "C" void kernel_launch(void* const* d_in, const int* in_sizes, int n_in,
                              void* d_out, int out_size, void* d_ws, size_t ws_size,
                              hipStream_t stream) {
    const float* X  = (const float*)d_in[0];
    const float* Km = (const float*)d_in[1];
    const float* Vm = (const float*)d_in[2];
    const float* Wo = (const float*)d_in[3];
    const float* bo = (const float*)d_in[4];
    const int* src  = (const int*)d_in[5];
    const int* dst  = (const int*)d_in[6];

    const int N = in_sizes[0] / DK;
    const int E = in_sizes[5];

    int* row_ptr = (int*)d_ws;                              // (N+1) ints
    const size_t kv_off = (((size_t)(N + 1) * 4) + 127) & ~(size_t)127;
    unsigned* KV = (unsigned*)((char*)d_ws + kv_off);       // N*DK uint32
    const size_t need = kv_off + (size_t)N * DK * 4;
    float* out = (float*)d_out;

    const int tb = 256;

    if (ws_size >= need) {
        const int nE4   = (E + 3) / 4;       // 4 edges per thread (dst scan)
        const int total = N * 8;             // one thread per uint4 (KV pack)
        const int prep_n = (nE4 > total) ? nE4 : total;
        prep_kernel<<<(prep_n + tb - 1) / tb, tb, 0, stream>>>(
            dst, (const float4*)Km, (const float4*)Vm, E, N,
            row_ptr, (uint4*)KV);
        const int grid = (N + 7) / 8;       // 8 nodes per block, 1 per wave
        gat_fused_kernel<<<grid, 512, 0, stream>>>(X, (const uint4*)KV, Wo, bo,
                                                   src, row_ptr, out, N);
    } else {
        build_row_ptr_kernel<<<(E + tb - 1) / tb, tb, 0, stream>>>(dst, E, N, row_ptr);
        const int grid = (N + 3) / 4;
        gat_node_f32_kernel<<<grid, 256, 0, stream>>>(X, Km, Vm, Wo, bo,
                                                      src, row_ptr, out, N);
    }
}